// Round 10
// baseline (335.697 us; speedup 1.0000x reference)
//
#include <hip/hip_runtime.h>

typedef unsigned int uint;
typedef unsigned short ushort;
typedef __bf16 v8bf __attribute__((ext_vector_type(8)));
typedef float v4f __attribute__((ext_vector_type(4)));
typedef float f2 __attribute__((ext_vector_type(2)));
typedef float f4v __attribute__((ext_vector_type(4)));

#define CCH 256
#define HH 336
#define WW 336
#define HWSZ (HH*WW)
#define NROI 2000
#define KDIM 12544       // 49*256
#define MPAD 2048
#define SPLITK 7
#define KSP (KDIM/SPLITK)   // 1792
#define NTRB (HWSZ/32)      // 3528 transpose blocks (32px tile)

__device__ __forceinline__ ushort bf16r(float f) {
  uint u = __float_as_uint(f);
  u += 0x7fffu + ((u >> 16) & 1u);   // RTNE
  return (ushort)(u >> 16);
}
__device__ __forceinline__ uint packbf(float a, float b) {
  return (uint)bf16r(a) | ((uint)bf16r(b) << 16);
}

typedef const __attribute__((address_space(1))) uint* gas_t;
typedef __attribute__((address_space(3))) uint* las_t;
__device__ __forceinline__ void async16(const void* g, void* l) {
  __builtin_amdgcn_global_load_lds((gas_t)g, (las_t)l, 16, 0, 0);
}

#define GLOAD4(dst, ptr)                                             \
  asm volatile("global_load_dwordx4 %0, %1, off" : "=v"(dst) : "v"(ptr))

// Round-10: transpose tile halved to 32px x 256ch. r9 counters: trprep
// 69us, occ 32.6%, VALU 4.8%, 1.87 TB/s for 129MB -> resident-block
// starved (32KB LDS capped 5 blk/CU, measured ~10 waves/CU). 16KB LDS ->
// 8 blk/CU (thread cap, 32 waves = 100%): ~2x the load-issuers in flight.
// Loads/thread 16->8 (still volatile-pinned); phase-2 tail halves.
// Swizzle identical (sw=(hwq&7)<<2 matches row>>2 on read). ftu bytes
// unchanged. Blocks 0..3527 transpose; 3528..3952 prep (r8 bodies).
__global__ __launch_bounds__(256) void k_trprep(const float* __restrict__ f,
                                                uint* __restrict__ ftu,
                                                const float* __restrict__ w1,
                                                uint* __restrict__ w1t_u,
                                                const float* __restrict__ w2,
                                                ushort* __restrict__ w2t,
                                                const int* __restrict__ rois,
                                                int* __restrict__ perm) {
  __shared__ uint SM[32 * 128];   // 16 KB shared pool
  int tid = threadIdx.x;
  if (blockIdx.x < NTRB) {
    // ---- transpose: features [256][336][336] fp32 -> ft [hw][c] bf16 ----
    uint* T = SM;
    int hw0 = blockIdx.x * 32;
    int hwq = tid & 7;              // hw-quad: pixels hw0+hwq*4 .. +3
    int cp = tid >> 3;              // 0..31
    const float* base = f + hw0 + hwq * 4;
    f4v va[4], vb[4];
#pragma unroll
    for (int j = 0; j < 4; ++j) {
      int cpair = j * 32 + cp;      // 0..127
      const float* pa = base + (size_t)(2 * cpair) * HWSZ;
      GLOAD4(va[j], pa);
      GLOAD4(vb[j], pa + HWSZ);
    }
    asm volatile("s_waitcnt vmcnt(0)" ::: "memory");
    __builtin_amdgcn_sched_barrier(0);
    int sw = (hwq & 7) << 2;        // swizzle for rows hwq*4..hwq*4+3
#pragma unroll
    for (int j = 0; j < 4; ++j) {
      int cs = (j * 32 + cp) ^ sw;
      T[(hwq * 4 + 0) * 128 + cs] = packbf(va[j].x, vb[j].x);
      T[(hwq * 4 + 1) * 128 + cs] = packbf(va[j].y, vb[j].y);
      T[(hwq * 4 + 2) * 128 + cs] = packbf(va[j].z, vb[j].z);
      T[(hwq * 4 + 3) * 128 + cs] = packbf(va[j].w, vb[j].w);
    }
    __syncthreads();
    int co = tid & 31, r = tid >> 5;   // 8 rows per iter
#pragma unroll
    for (int i = 0; i < 4; ++i) {
      int row = i * 8 + r;
      int col = (co * 4) ^ (((row >> 2) & 7) << 2);   // inverse swizzle
      uint4 v = *(const uint4*)&T[row * 128 + col];
      *(uint4*)(ftu + (size_t)(hw0 + row) * 128 + co * 4) = v;
    }
    return;
  }
  int b = blockIdx.x - NTRB;        // 0..424
  if (b < 392) {
    // w1 [12544][256] fp32 (k=c*49+bin) -> w1t bf16 [n][k'], k'=bin*256+c
    // LDS need: 32*258*2 = 16512 B > 16384 -> use [32][256] (16384 B).
    // Bank profile: phase-1 writes stride 256 ushort = 2-way (free, m136);
    // phase-2 reads T[2cc][nn],T[2cc+1][nn] unchanged semantics.
    ushort (*T)[256] = reinterpret_cast<ushort (*)[256]>(SM);  // 16384 B
    int bin = b % 49;
    int c0 = (b / 49) * 32;
    int n = tid;
    for (int i = 0; i < 32; ++i)
      T[i][n] = bf16r(w1[(size_t)((c0 + i) * 49 + bin) * 256 + n]);
    __syncthreads();
    int cc = tid & 15;
    int nb = tid >> 4;
    for (int rep = 0; rep < 16; ++rep) {
      int nn = rep * 16 + nb;
      uint v = (uint)T[2 * cc][nn] | ((uint)T[2 * cc + 1][nn] << 16);
      w1t_u[(size_t)nn * (KDIM / 2) + bin * 128 + c0 / 2 + cc] = v;
    }
  } else if (b < 424) {
    // w2 [256][256] -> w2t bf16 [n][k]
    int n = (b - 392) * 8 + (tid >> 5);
    for (int kl = 0; kl < 8; ++kl) {
      int k = kl * 32 + (tid & 31);
      w2t[n * 256 + k] = bf16r(w2[k * 256 + n]);
    }
  } else {
    // counting-sort ROIs by spatial tile (8x8 grid of 42px) -> perm
    int* hist = (int*)SM;                    // 256 B
    int* keys = hist + 64;                   // 8000 B (ends 8256 < 16384)
    if (tid < 64) hist[tid] = 0;
    __syncthreads();
    for (int i = tid; i < NROI; i += 256) {
      int x1 = rois[i * 4 + 0], y1 = rois[i * 4 + 1];
      int x2 = rois[i * 4 + 2], y2 = rois[i * 4 + 3];
      int cx = (x1 + x2) >> 1, cy = (y1 + y2) >> 1;
      int k = (cy / 42) * 8 + (cx / 42);
      keys[i] = k;
      atomicAdd(&hist[k], 1);
    }
    __syncthreads();
    if (tid < 64) {               // wave-0 exclusive prefix scan
      int v = hist[tid];
      int s = v;
#pragma unroll
      for (int d = 1; d < 64; d <<= 1) {
        int t2 = __shfl_up(s, d, 64);
        if (tid >= d) s += t2;
      }
      hist[tid] = s - v;
    }
    __syncthreads();
    for (int i = tid; i < NROI; i += 256) {
      int pos = atomicAdd(&hist[keys[i]], 1);
      perm[pos] = i;
    }
  }
}

// Round-9 k_pool: depth-2 pipelined chunks (counted vmcnt), unchanged.
__device__ __forceinline__ void pkacc(f2& acc, uint u) {
  f2 t;
  t.x = __uint_as_float(u << 16);
  t.y = __uint_as_float(u & 0xffff0000u);
  asm("v_pk_add_f32 %0, %1, %0" : "+v"(acc) : "v"(t));
}
#define UNPK2(S, u) do { pkacc(S[0], (u).x); pkacc(S[1], (u).y); } while (0)

#define GL(dst, ptr, OFF)                                            \
  asm volatile("global_load_dwordx2 %0, %1, off offset:" #OFF        \
               : "=v"(dst) : "v"(ptr))

template <int N> __device__ __forceinline__ void waitvm() {
  if constexpr (N == 0)       asm volatile("s_waitcnt vmcnt(0)" ::: "memory");
  else if constexpr (N == 8)  asm volatile("s_waitcnt vmcnt(8)" ::: "memory");
  else if constexpr (N == 12) asm volatile("s_waitcnt vmcnt(12)" ::: "memory");
  else if constexpr (N == 16) asm volatile("s_waitcnt vmcnt(16)" ::: "memory");
  else                        asm volatile("s_waitcnt vmcnt(0)" ::: "memory");
}

struct BinState {
  int b, lo_cur, hi_cur, lo_next;
  f2 P[2], Lc[2], Ln[2];
};

template <int RH, int CW>
__device__ __forceinline__ void issue_chunk(uint2 (&buf)[CW][RH],
                                            const uint2* (&pr)[RH]) {
#pragma unroll
  for (int r = 0; r < RH; ++r) {
    GL(buf[0][r], pr[r], 0);
    if constexpr (CW > 1) GL(buf[1][r], pr[r], 512);
    if constexpr (CW > 2) GL(buf[2][r], pr[r], 1024);
    if constexpr (CW > 3) GL(buf[3][r], pr[r], 1536);
    if constexpr (CW > 4) GL(buf[4][r], pr[r], 2048);
    if constexpr (CW > 5) GL(buf[5][r], pr[r], 2560);
    if constexpr (CW > 6) GL(buf[6][r], pr[r], 3072);
    if constexpr (CW > 7) GL(buf[7][r], pr[r], 3584);
  }
#pragma unroll
  for (int r = 0; r < RH; ++r) pr[r] += CW * 64;
}

template <int RH, int CW>
__device__ __forceinline__ void consume_chunk(const uint2 (&v)[CW][RH], int xc,
                                              int xend, int x1, int Lw,
                                              float invr, uint ob,
                                              uint2* __restrict__ rfu2,
                                              BinState& S) {
#pragma unroll
  for (int c = 0; c < CW; ++c) {
    int x = xc + c;
    if (x < xend) {
#pragma unroll
      for (int r = 0; r < RH; ++r) UNPK2(S.P, v[c][r]);
      int xp = x + 1;
      if (xp == S.lo_next) { S.Ln[0] = S.P[0]; S.Ln[1] = S.P[1]; }
      while (S.b < 7 && xp == S.hi_cur) {
        float inv = invr / (float)(S.hi_cur - S.lo_cur);
        uint2 o;
        o.x = packbf((S.P[0].x - S.Lc[0].x) * inv, (S.P[0].y - S.Lc[0].y) * inv);
        o.y = packbf((S.P[1].x - S.Lc[1].x) * inv, (S.P[1].y - S.Lc[1].y) * inv);
        rfu2[ob + S.b * 64] = o;
        ++S.b;
        S.Lc[0] = S.Ln[0]; S.Lc[1] = S.Ln[1];
        S.lo_cur = S.lo_next;
        S.hi_cur = x1 + ((S.b + 1) * Lw + 6) / 7;
        S.lo_next = x1 + ((S.b + 1) * Lw) / 7;
        if (xp == S.lo_next) { S.Ln[0] = S.P[0]; S.Ln[1] = S.P[1]; }
      }
    }
  }
}

template <int RH>
__device__ __forceinline__ void init_state(BinState& S, int x1, int Lw) {
  S.b = 0;
  S.lo_cur = x1;
  S.hi_cur = x1 + (Lw + 6) / 7;
  S.lo_next = x1 + Lw / 7;
  S.P[0] = (f2){0.f, 0.f}; S.P[1] = (f2){0.f, 0.f};
  S.Lc[0] = (f2){0.f, 0.f}; S.Lc[1] = (f2){0.f, 0.f};
  S.Ln[0] = (f2){0.f, 0.f}; S.Ln[1] = (f2){0.f, 0.f};
}

// depth-2 double-buffered walk
template <int RH, int CW>
__device__ void pool_db(const uint2* __restrict__ ftu2,
                        uint2* __restrict__ rfu2,
                        int x1, int Lw, int ylo, int lane, uint ob) {
  const uint2* pr[RH];
#pragma unroll
  for (int r = 0; r < RH; ++r)
    pr[r] = ftu2 + (size_t)((ylo + r) * WW + x1) * 64 + lane;
  int xend = x1 + Lw;
  BinState S;
  init_state<RH>(S, x1, Lw);
  const float invr = 1.0f / (float)RH;
  uint2 va[CW][RH], vb[CW][RH];
  issue_chunk<RH, CW>(va, pr);
  int xc = x1;
  for (;;) {
    int xn = xc + CW;
    if (xn < xend) { issue_chunk<RH, CW>(vb, pr); waitvm<CW * RH>(); }
    else waitvm<0>();
    __builtin_amdgcn_sched_barrier(0);
    consume_chunk<RH, CW>(va, xc, xend, x1, Lw, invr, ob, rfu2, S);
    if (xn >= xend) return;
    xc = xn;
    xn = xc + CW;
    if (xn < xend) { issue_chunk<RH, CW>(va, pr); waitvm<CW * RH>(); }
    else waitvm<0>();
    __builtin_amdgcn_sched_barrier(0);
    consume_chunk<RH, CW>(vb, xc, xend, x1, Lw, invr, ob, rfu2, S);
    if (xn >= xend) return;
    xc = xn;
  }
}

// depth-1 single-buffer walk for large RH
template <int RH, int CW>
__device__ void pool_sb(const uint2* __restrict__ ftu2,
                        uint2* __restrict__ rfu2,
                        int x1, int Lw, int ylo, int lane, uint ob) {
  const uint2* pr[RH];
#pragma unroll
  for (int r = 0; r < RH; ++r)
    pr[r] = ftu2 + (size_t)((ylo + r) * WW + x1) * 64 + lane;
  int xend = x1 + Lw;
  BinState S;
  init_state<RH>(S, x1, Lw);
  const float invr = 1.0f / (float)RH;
  uint2 va[CW][RH];
  for (int xc = x1; xc < xend; xc += CW) {
    issue_chunk<RH, CW>(va, pr);
    waitvm<0>();
    __builtin_amdgcn_sched_barrier(0);
    consume_chunk<RH, CW>(va, xc, xend, x1, Lw, invr, ob, rfu2, S);
  }
}

__global__ __launch_bounds__(64) void k_pool(const int* __restrict__ rois,
                                             const int* __restrict__ perm,
                                             const uint2* __restrict__ ftu2,
                                             uint2* __restrict__ rfu2) {
  int L = blockIdx.x;
  int i = L >> 3;
  int slot = (L & 7) * 250 + i / 7;
  int by = i % 7;
  int n = perm[slot];
  int lane = threadIdx.x;            // channel-quad 0..63
  int x1 = rois[n * 4 + 0], y1 = rois[n * 4 + 1];
  int x2 = rois[n * 4 + 2], y2 = rois[n * 4 + 3];
  int Lw = x2 - x1 + 1, Lh = y2 - y1 + 1;
  int ylo = y1 + (by * Lh) / 7;
  int yhi = y1 + ((by + 1) * Lh + 6) / 7;
  int rh = yhi - ylo;                // 1..7
  uint ob = ((uint)n * 49 + (uint)by * 7) * 64 + lane;
  switch (rh) {
    case 1: pool_db<1, 8>(ftu2, rfu2, x1, Lw, ylo, lane, ob); break;
    case 2: pool_db<2, 8>(ftu2, rfu2, x1, Lw, ylo, lane, ob); break;
    case 3: pool_db<3, 4>(ftu2, rfu2, x1, Lw, ylo, lane, ob); break;
    case 4: pool_db<4, 4>(ftu2, rfu2, x1, Lw, ylo, lane, ob); break;
    case 5: pool_sb<5, 4>(ftu2, rfu2, x1, Lw, ylo, lane, ob); break;
    case 6: pool_sb<6, 4>(ftu2, rfu2, x1, Lw, ylo, lane, ob); break;
    default: pool_sb<7, 4>(ftu2, rfu2, x1, Lw, ylo, lane, ob); break;
  }
}

// NT GEMM: A=rf [2048][12544], B=w1t [256][12544], 64x128 tiles, split-K=7
__global__ __launch_bounds__(256) void k_gemm1(const ushort* __restrict__ A,
                                               const ushort* __restrict__ B,
                                               float* __restrict__ P) {
  __shared__ ushort As[64 * 64];
  __shared__ ushort Bs[128 * 64];
  int m0 = blockIdx.x * 64;
  int n0 = blockIdx.y * 128;
  int ks = blockIdx.z;
  int k0 = ks * KSP;
  int tid = threadIdx.x;
  int lane = tid & 63, wv = tid >> 6;
  int wm = wv & 1, wn = wv >> 1;
  int lm = lane & 15, quad = lane >> 4;
  int srow = tid >> 3, scol = (tid & 7) * 8;
  v4f acc[2][4];
#pragma unroll
  for (int i = 0; i < 2; ++i)
#pragma unroll
    for (int j = 0; j < 4; ++j) acc[i][j] = (v4f){0.f, 0.f, 0.f, 0.f};
  const ushort* Ab = A + (size_t)(m0 + srow) * KDIM + k0 + scol;
  const ushort* Bb = B + (size_t)(n0 + srow) * KDIM + k0 + scol;
  for (int kt = 0; kt < KSP / 64; ++kt) {
    __syncthreads();
#pragma unroll
    for (int r = 0; r < 2; ++r)
      async16(Ab + (size_t)(r * 32) * KDIM + kt * 64, &As[(srow + r * 32) * 64 + scol]);
#pragma unroll
    for (int r = 0; r < 4; ++r)
      async16(Bb + (size_t)(r * 32) * KDIM + kt * 64, &Bs[(srow + r * 32) * 64 + scol]);
    __syncthreads();
#pragma unroll
    for (int kk = 0; kk < 64; kk += 32) {
      v8bf a[2], b[4];
#pragma unroll
      for (int i = 0; i < 2; ++i)
        a[i] = *(const v8bf*)&As[(wm * 32 + i * 16 + lm) * 64 + kk + quad * 8];
#pragma unroll
      for (int j = 0; j < 4; ++j)
        b[j] = *(const v8bf*)&Bs[(wn * 64 + j * 16 + lm) * 64 + kk + quad * 8];
#pragma unroll
      for (int i = 0; i < 2; ++i)
#pragma unroll
        for (int j = 0; j < 4; ++j)
          acc[i][j] = __builtin_amdgcn_mfma_f32_16x16x32_bf16(a[i], b[j], acc[i][j], 0, 0, 0);
    }
  }
  float* Pb = P + (size_t)ks * MPAD * 256;
#pragma unroll
  for (int i = 0; i < 2; ++i)
#pragma unroll
    for (int j = 0; j < 4; ++j) {
      int row = m0 + wm * 32 + i * 16 + quad * 4;
      int col = n0 + wn * 64 + j * 16 + lm;
#pragma unroll
      for (int r = 0; r < 4; ++r)
        Pb[(size_t)(row + r) * 256 + col] = acc[i][j][r];
    }
}

// GEMM2 with fused split-K reduce: A-tile = sum of 7 P-partials + b1 + relu,
// packed bf16 into XOR-swizzled LDS; then K=256 MFMA loop + cls/reg heads.
__global__ __launch_bounds__(256) void k_gemm2(const float* __restrict__ P,
                                               const float* __restrict__ b1,
                                               const ushort* __restrict__ w2t,
                                               const float* __restrict__ b2,
                                               const float* __restrict__ wcls,
                                               const float* __restrict__ bcls,
                                               const float* __restrict__ wreg,
                                               const float* __restrict__ breg,
                                               float* __restrict__ out) {
  __shared__ ushort HsA[64 * 256];   // 32 KB swizzled A (bf16)
  __shared__ ushort Bs2[256 * 64];
  __shared__ float Hs[64 * 257];
  int tid = threadIdx.x;
  int r0 = blockIdx.x * 64;
  int lane = tid & 63, wv = tid >> 6;
  int lm = lane & 15, quad = lane >> 4;
  int srow = tid >> 3, scol = (tid & 7) * 8;
  // ---- stage A: split-K sum + b1 + relu -> bf16 LDS ----
  uint* H = (uint*)HsA;
  for (int it = 0; it < 16; ++it) {
    int e = it * 256 + tid;          // 0..4095
    int row = e >> 6;                // 0..63
    int c4 = e & 63;                 // float4 column (16B = 4 ch)
    float4 s = {0.f, 0.f, 0.f, 0.f};
#pragma unroll
    for (int ks = 0; ks < SPLITK; ++ks) {
      float4 v = ((const float4*)P)[((size_t)ks * MPAD + r0 + row) * 64 + c4];
      s.x += v.x; s.y += v.y; s.z += v.z; s.w += v.w;
    }
    int col = c4 * 4;
    s.x = fmaxf(s.x + b1[col + 0], 0.f);
    s.y = fmaxf(s.y + b1[col + 1], 0.f);
    s.z = fmaxf(s.z + b1[col + 2], 0.f);
    s.w = fmaxf(s.w + b1[col + 3], 0.f);
    int cs = (c4 >> 1) ^ (row & 7);            // 16B-chunk swizzle
    int ui = row * 128 + cs * 4 + (c4 & 1) * 2;
    H[ui]     = packbf(s.x, s.y);
    H[ui + 1] = packbf(s.z, s.w);
  }
  v4f acc[16];
#pragma unroll
  for (int j = 0; j < 16; ++j) acc[j] = (v4f){0.f, 0.f, 0.f, 0.f};
  int arow = wv * 16 + lm;
  int asw = (arow & 7) << 3;         // ushort-index swizzle (8 bf16 = 16B)
  for (int kt = 0; kt < 4; ++kt) {
    __syncthreads();
#pragma unroll
    for (int r = 0; r < 8; ++r)
      async16(w2t + (size_t)(srow + r * 32) * 256 + kt * 64 + scol,
              &Bs2[(srow + r * 32) * 64 + scol]);
    __syncthreads();
#pragma unroll
    for (int kk = 0; kk < 64; kk += 32) {
      v8bf a = *(const v8bf*)&HsA[arow * 256 + ((kt * 64 + kk + quad * 8) ^ asw)];
#pragma unroll
      for (int j = 0; j < 16; ++j) {
        v8bf b = *(const v8bf*)&Bs2[(j * 16 + lm) * 64 + kk + quad * 8];
        acc[j] = __builtin_amdgcn_mfma_f32_16x16x32_bf16(a, b, acc[j], 0, 0, 0);
      }
    }
  }
#pragma unroll
  for (int j = 0; j < 16; ++j) {
    int nn = j * 16 + lm;
    float bb = b2[nn];
#pragma unroll
    for (int r = 0; r < 4; ++r) {
      int row = wv * 16 + quad * 4 + r;
      Hs[row * 257 + nn] = fmaxf(acc[j][r] + bb, 0.f);
    }
  }
  __syncthreads();
  for (int o = tid; o < 384; o += 256) {
    int hd = o >> 6, r = o & 63;
    int grow = r0 + r;
    float d = 0.f;
    if (hd < 2) {
      for (int k = 0; k < 256; ++k) d += Hs[r * 257 + k] * wcls[k * 2 + hd];
      d += bcls[hd];
      if (grow < NROI) out[grow * 2 + hd] = d;
    } else {
      int h4 = hd - 2;
      for (int k = 0; k < 256; ++k) d += Hs[r * 257 + k] * wreg[k * 4 + h4];
      d += breg[h4];
      if (grow < NROI) out[4000 + grow * 4 + h4] = d;
    }
  }
}

extern "C" void kernel_launch(void* const* d_in, const int* in_sizes, int n_in,
                              void* d_out, int out_size, void* d_ws, size_t ws_size,
                              hipStream_t stream) {
  const float* features = (const float*)d_in[0];
  const int* rois = (const int*)d_in[1];
  const float* w1 = (const float*)d_in[2];
  const float* b1 = (const float*)d_in[3];
  const float* w2 = (const float*)d_in[4];
  const float* b2 = (const float*)d_in[5];
  const float* wcls = (const float*)d_in[6];
  const float* bcls = (const float*)d_in[7];
  const float* wreg = (const float*)d_in[8];
  const float* breg = (const float*)d_in[9];
  char* ws = (char*)d_ws;
  ushort* ft  = (ushort*)(ws + 0);          // 57,802,752 B
  ushort* w1t = (ushort*)(ws + 57802752);   //  6,422,528 B
  ushort* w2t = (ushort*)(ws + 64225280);   //    131,072 B
  ushort* rf  = (ushort*)(ws + 64356352);   // 51,380,224 B (2048 rows; rows
                                            // 2000+ are GEMM padding)
  // perm lives in rf's padding rows (read by gemm1 as harmless tiny bf16)
  int*    perm = (int*)(ws + 64356352 + (size_t)NROI * KDIM * 2);
  float*  P   = (float*)(ws + 115736576);   // 14,680,064 B used
  float* out = (float*)d_out;

  hipLaunchKernelGGL(k_trprep, dim3(NTRB + 425), dim3(256), 0, stream,
                     features, (uint*)ft, w1, (uint*)w1t, w2, w2t, rois, perm);
  hipLaunchKernelGGL(k_pool, dim3(NROI * 7), dim3(64), 0, stream, rois, perm,
                     (const uint2*)ft, (uint2*)rf);
  hipLaunchKernelGGL(k_gemm1, dim3(32, 2, SPLITK), dim3(256), 0, stream, rf, w1t, P);
  hipLaunchKernelGGL(k_gemm2, dim3(32), dim3(256), 0, stream, P, b1, w2t, b2,
                     wcls, bcls, wreg, breg, out);
}

// Round 11
// 335.105 us; speedup vs baseline: 1.0018x; 1.0018x over previous
//
#include <hip/hip_runtime.h>

typedef unsigned int uint;
typedef unsigned short ushort;
typedef __bf16 v8bf __attribute__((ext_vector_type(8)));
typedef float v4f __attribute__((ext_vector_type(4)));
typedef float f2 __attribute__((ext_vector_type(2)));
typedef float f4v __attribute__((ext_vector_type(4)));

#define CCH 256
#define HH 336
#define WW 336
#define HWSZ (HH*WW)
#define NROI 2000
#define KDIM 12544       // 49*256
#define MPAD 2048
#define SPLITK 7
#define KSP (KDIM/SPLITK)   // 1792
#define NTRB (HWSZ/64)      // 1764 transpose blocks (64px tile — r9 best)

__device__ __forceinline__ ushort bf16r(float f) {
  uint u = __float_as_uint(f);
  u += 0x7fffu + ((u >> 16) & 1u);   // RTNE
  return (ushort)(u >> 16);
}
__device__ __forceinline__ uint packbf(float a, float b) {
  return (uint)bf16r(a) | ((uint)bf16r(b) << 16);
}

typedef const __attribute__((address_space(1))) uint* gas_t;
typedef __attribute__((address_space(3))) uint* las_t;
__device__ __forceinline__ void async16(const void* g, void* l) {
  __builtin_amdgcn_global_load_lds((gas_t)g, (las_t)l, 16, 0, 0);
}

#define GLOAD4(dst, ptr)                                             \
  asm volatile("global_load_dwordx4 %0, %1, off" : "=v"(dst) : "v"(ptr))

// r9 config (measured session best, 330.46us): transpose 64px tile (32KB
// LDS). r10's A/B proved occupancy is NOT the lever here (occ 32.6->58.8%
// with dur 69->74us): the kernel is bound by scattered-read transaction
// latency (4 separate 256B segments per wave-load), invariant across tile
// size / load pinning / occupancy. Keep the conflict-free [32][258] w1
// layout (r10's [32][256] was 16-way bank-conflicted on phase-2 reads).
__global__ __launch_bounds__(256) void k_trprep(const float* __restrict__ f,
                                                uint* __restrict__ ftu,
                                                const float* __restrict__ w1,
                                                uint* __restrict__ w1t_u,
                                                const float* __restrict__ w2,
                                                ushort* __restrict__ w2t,
                                                const int* __restrict__ rois,
                                                int* __restrict__ perm) {
  __shared__ uint SM[64 * 128];   // 32 KB shared pool
  int tid = threadIdx.x;
  if (blockIdx.x < NTRB) {
    // ---- transpose: features [256][336][336] fp32 -> ft [hw][c] bf16 ----
    uint* T = SM;
    int hw0 = blockIdx.x * 64;
    int hwq = tid & 15;             // hw-quad: pixels hw0+hwq*4 .. +3
    int cp = tid >> 4;              // 0..15
    const float* base = f + hw0 + hwq * 4;
    f4v va[8], vb[8];
#pragma unroll
    for (int j = 0; j < 8; ++j) {
      int cpair = j * 16 + cp;      // 0..127
      const float* pa = base + (size_t)(2 * cpair) * HWSZ;
      GLOAD4(va[j], pa);
      GLOAD4(vb[j], pa + HWSZ);
    }
    asm volatile("s_waitcnt vmcnt(0)" ::: "memory");
    __builtin_amdgcn_sched_barrier(0);
    int sw = (hwq & 7) << 2;        // swizzle for rows hwq*4..hwq*4+3
#pragma unroll
    for (int j = 0; j < 8; ++j) {
      int cs = (j * 16 + cp) ^ sw;
      T[(hwq * 4 + 0) * 128 + cs] = packbf(va[j].x, vb[j].x);
      T[(hwq * 4 + 1) * 128 + cs] = packbf(va[j].y, vb[j].y);
      T[(hwq * 4 + 2) * 128 + cs] = packbf(va[j].z, vb[j].z);
      T[(hwq * 4 + 3) * 128 + cs] = packbf(va[j].w, vb[j].w);
    }
    __syncthreads();
    int co = tid & 31, r = tid >> 5;   // 8 rows per iter
#pragma unroll
    for (int i = 0; i < 8; ++i) {
      int row = i * 8 + r;
      int col = (co * 4) ^ (((row >> 2) & 7) << 2);   // inverse swizzle
      uint4 v = *(const uint4*)&T[row * 128 + col];
      *(uint4*)(ftu + (size_t)(hw0 + row) * 128 + co * 4) = v;
    }
    return;
  }
  int b = blockIdx.x - NTRB;        // 0..424
  if (b < 392) {
    // w1 [12544][256] fp32 (k=c*49+bin) -> w1t bf16 [n][k'], k'=bin*256+c
    ushort (*T)[258] = reinterpret_cast<ushort (*)[258]>(SM);  // 16512 B
    int bin = b % 49;
    int c0 = (b / 49) * 32;
    int n = tid;
    for (int i = 0; i < 32; ++i)
      T[i][n] = bf16r(w1[(size_t)((c0 + i) * 49 + bin) * 256 + n]);
    __syncthreads();
    int cc = tid & 15;
    int nb = tid >> 4;
    for (int rep = 0; rep < 16; ++rep) {
      int nn = rep * 16 + nb;
      uint v = (uint)T[2 * cc][nn] | ((uint)T[2 * cc + 1][nn] << 16);
      w1t_u[(size_t)nn * (KDIM / 2) + bin * 128 + c0 / 2 + cc] = v;
    }
  } else if (b < 424) {
    // w2 [256][256] -> w2t bf16 [n][k]
    int n = (b - 392) * 8 + (tid >> 5);
    for (int kl = 0; kl < 8; ++kl) {
      int k = kl * 32 + (tid & 31);
      w2t[n * 256 + k] = bf16r(w2[k * 256 + n]);
    }
  } else {
    // counting-sort ROIs by spatial tile (8x8 grid of 42px) -> perm
    int* hist = (int*)((char*)SM + 16512);   // 256 B
    int* keys = hist + 64;                   // 8000 B (ends 24768 < 32768)
    if (tid < 64) hist[tid] = 0;
    __syncthreads();
    for (int i = tid; i < NROI; i += 256) {
      int x1 = rois[i * 4 + 0], y1 = rois[i * 4 + 1];
      int x2 = rois[i * 4 + 2], y2 = rois[i * 4 + 3];
      int cx = (x1 + x2) >> 1, cy = (y1 + y2) >> 1;
      int k = (cy / 42) * 8 + (cx / 42);
      keys[i] = k;
      atomicAdd(&hist[k], 1);
    }
    __syncthreads();
    if (tid < 64) {               // wave-0 exclusive prefix scan
      int v = hist[tid];
      int s = v;
#pragma unroll
      for (int d = 1; d < 64; d <<= 1) {
        int t2 = __shfl_up(s, d, 64);
        if (tid >= d) s += t2;
      }
      hist[tid] = s - v;
    }
    __syncthreads();
    for (int i = tid; i < NROI; i += 256) {
      int pos = atomicAdd(&hist[keys[i]], 1);
      perm[pos] = i;
    }
  }
}

// Round-9 k_pool: depth-2 pipelined chunks (counted vmcnt), unchanged.
__device__ __forceinline__ void pkacc(f2& acc, uint u) {
  f2 t;
  t.x = __uint_as_float(u << 16);
  t.y = __uint_as_float(u & 0xffff0000u);
  asm("v_pk_add_f32 %0, %1, %0" : "+v"(acc) : "v"(t));
}
#define UNPK2(S, u) do { pkacc(S[0], (u).x); pkacc(S[1], (u).y); } while (0)

#define GL(dst, ptr, OFF)                                            \
  asm volatile("global_load_dwordx2 %0, %1, off offset:" #OFF        \
               : "=v"(dst) : "v"(ptr))

template <int N> __device__ __forceinline__ void waitvm() {
  if constexpr (N == 0)       asm volatile("s_waitcnt vmcnt(0)" ::: "memory");
  else if constexpr (N == 8)  asm volatile("s_waitcnt vmcnt(8)" ::: "memory");
  else if constexpr (N == 12) asm volatile("s_waitcnt vmcnt(12)" ::: "memory");
  else if constexpr (N == 16) asm volatile("s_waitcnt vmcnt(16)" ::: "memory");
  else                        asm volatile("s_waitcnt vmcnt(0)" ::: "memory");
}

struct BinState {
  int b, lo_cur, hi_cur, lo_next;
  f2 P[2], Lc[2], Ln[2];
};

template <int RH, int CW>
__device__ __forceinline__ void issue_chunk(uint2 (&buf)[CW][RH],
                                            const uint2* (&pr)[RH]) {
#pragma unroll
  for (int r = 0; r < RH; ++r) {
    GL(buf[0][r], pr[r], 0);
    if constexpr (CW > 1) GL(buf[1][r], pr[r], 512);
    if constexpr (CW > 2) GL(buf[2][r], pr[r], 1024);
    if constexpr (CW > 3) GL(buf[3][r], pr[r], 1536);
    if constexpr (CW > 4) GL(buf[4][r], pr[r], 2048);
    if constexpr (CW > 5) GL(buf[5][r], pr[r], 2560);
    if constexpr (CW > 6) GL(buf[6][r], pr[r], 3072);
    if constexpr (CW > 7) GL(buf[7][r], pr[r], 3584);
  }
#pragma unroll
  for (int r = 0; r < RH; ++r) pr[r] += CW * 64;
}

template <int RH, int CW>
__device__ __forceinline__ void consume_chunk(const uint2 (&v)[CW][RH], int xc,
                                              int xend, int x1, int Lw,
                                              float invr, uint ob,
                                              uint2* __restrict__ rfu2,
                                              BinState& S) {
#pragma unroll
  for (int c = 0; c < CW; ++c) {
    int x = xc + c;
    if (x < xend) {
#pragma unroll
      for (int r = 0; r < RH; ++r) UNPK2(S.P, v[c][r]);
      int xp = x + 1;
      if (xp == S.lo_next) { S.Ln[0] = S.P[0]; S.Ln[1] = S.P[1]; }
      while (S.b < 7 && xp == S.hi_cur) {
        float inv = invr / (float)(S.hi_cur - S.lo_cur);
        uint2 o;
        o.x = packbf((S.P[0].x - S.Lc[0].x) * inv, (S.P[0].y - S.Lc[0].y) * inv);
        o.y = packbf((S.P[1].x - S.Lc[1].x) * inv, (S.P[1].y - S.Lc[1].y) * inv);
        rfu2[ob + S.b * 64] = o;
        ++S.b;
        S.Lc[0] = S.Ln[0]; S.Lc[1] = S.Ln[1];
        S.lo_cur = S.lo_next;
        S.hi_cur = x1 + ((S.b + 1) * Lw + 6) / 7;
        S.lo_next = x1 + ((S.b + 1) * Lw) / 7;
        if (xp == S.lo_next) { S.Ln[0] = S.P[0]; S.Ln[1] = S.P[1]; }
      }
    }
  }
}

template <int RH>
__device__ __forceinline__ void init_state(BinState& S, int x1, int Lw) {
  S.b = 0;
  S.lo_cur = x1;
  S.hi_cur = x1 + (Lw + 6) / 7;
  S.lo_next = x1 + Lw / 7;
  S.P[0] = (f2){0.f, 0.f}; S.P[1] = (f2){0.f, 0.f};
  S.Lc[0] = (f2){0.f, 0.f}; S.Lc[1] = (f2){0.f, 0.f};
  S.Ln[0] = (f2){0.f, 0.f}; S.Ln[1] = (f2){0.f, 0.f};
}

// depth-2 double-buffered walk
template <int RH, int CW>
__device__ void pool_db(const uint2* __restrict__ ftu2,
                        uint2* __restrict__ rfu2,
                        int x1, int Lw, int ylo, int lane, uint ob) {
  const uint2* pr[RH];
#pragma unroll
  for (int r = 0; r < RH; ++r)
    pr[r] = ftu2 + (size_t)((ylo + r) * WW + x1) * 64 + lane;
  int xend = x1 + Lw;
  BinState S;
  init_state<RH>(S, x1, Lw);
  const float invr = 1.0f / (float)RH;
  uint2 va[CW][RH], vb[CW][RH];
  issue_chunk<RH, CW>(va, pr);
  int xc = x1;
  for (;;) {
    int xn = xc + CW;
    if (xn < xend) { issue_chunk<RH, CW>(vb, pr); waitvm<CW * RH>(); }
    else waitvm<0>();
    __builtin_amdgcn_sched_barrier(0);
    consume_chunk<RH, CW>(va, xc, xend, x1, Lw, invr, ob, rfu2, S);
    if (xn >= xend) return;
    xc = xn;
    xn = xc + CW;
    if (xn < xend) { issue_chunk<RH, CW>(va, pr); waitvm<CW * RH>(); }
    else waitvm<0>();
    __builtin_amdgcn_sched_barrier(0);
    consume_chunk<RH, CW>(vb, xc, xend, x1, Lw, invr, ob, rfu2, S);
    if (xn >= xend) return;
    xc = xn;
  }
}

// depth-1 single-buffer walk for large RH
template <int RH, int CW>
__device__ void pool_sb(const uint2* __restrict__ ftu2,
                        uint2* __restrict__ rfu2,
                        int x1, int Lw, int ylo, int lane, uint ob) {
  const uint2* pr[RH];
#pragma unroll
  for (int r = 0; r < RH; ++r)
    pr[r] = ftu2 + (size_t)((ylo + r) * WW + x1) * 64 + lane;
  int xend = x1 + Lw;
  BinState S;
  init_state<RH>(S, x1, Lw);
  const float invr = 1.0f / (float)RH;
  uint2 va[CW][RH];
  for (int xc = x1; xc < xend; xc += CW) {
    issue_chunk<RH, CW>(va, pr);
    waitvm<0>();
    __builtin_amdgcn_sched_barrier(0);
    consume_chunk<RH, CW>(va, xc, xend, x1, Lw, invr, ob, rfu2, S);
  }
}

__global__ __launch_bounds__(64) void k_pool(const int* __restrict__ rois,
                                             const int* __restrict__ perm,
                                             const uint2* __restrict__ ftu2,
                                             uint2* __restrict__ rfu2) {
  int L = blockIdx.x;
  int i = L >> 3;
  int slot = (L & 7) * 250 + i / 7;
  int by = i % 7;
  int n = perm[slot];
  int lane = threadIdx.x;            // channel-quad 0..63
  int x1 = rois[n * 4 + 0], y1 = rois[n * 4 + 1];
  int x2 = rois[n * 4 + 2], y2 = rois[n * 4 + 3];
  int Lw = x2 - x1 + 1, Lh = y2 - y1 + 1;
  int ylo = y1 + (by * Lh) / 7;
  int yhi = y1 + ((by + 1) * Lh + 6) / 7;
  int rh = yhi - ylo;                // 1..7
  uint ob = ((uint)n * 49 + (uint)by * 7) * 64 + lane;
  switch (rh) {
    case 1: pool_db<1, 8>(ftu2, rfu2, x1, Lw, ylo, lane, ob); break;
    case 2: pool_db<2, 8>(ftu2, rfu2, x1, Lw, ylo, lane, ob); break;
    case 3: pool_db<3, 4>(ftu2, rfu2, x1, Lw, ylo, lane, ob); break;
    case 4: pool_db<4, 4>(ftu2, rfu2, x1, Lw, ylo, lane, ob); break;
    case 5: pool_sb<5, 4>(ftu2, rfu2, x1, Lw, ylo, lane, ob); break;
    case 6: pool_sb<6, 4>(ftu2, rfu2, x1, Lw, ylo, lane, ob); break;
    default: pool_sb<7, 4>(ftu2, rfu2, x1, Lw, ylo, lane, ob); break;
  }
}

// NT GEMM: A=rf [2048][12544], B=w1t [256][12544], 64x128 tiles, split-K=7
__global__ __launch_bounds__(256) void k_gemm1(const ushort* __restrict__ A,
                                               const ushort* __restrict__ B,
                                               float* __restrict__ P) {
  __shared__ ushort As[64 * 64];
  __shared__ ushort Bs[128 * 64];
  int m0 = blockIdx.x * 64;
  int n0 = blockIdx.y * 128;
  int ks = blockIdx.z;
  int k0 = ks * KSP;
  int tid = threadIdx.x;
  int lane = tid & 63, wv = tid >> 6;
  int wm = wv & 1, wn = wv >> 1;
  int lm = lane & 15, quad = lane >> 4;
  int srow = tid >> 3, scol = (tid & 7) * 8;
  v4f acc[2][4];
#pragma unroll
  for (int i = 0; i < 2; ++i)
#pragma unroll
    for (int j = 0; j < 4; ++j) acc[i][j] = (v4f){0.f, 0.f, 0.f, 0.f};
  const ushort* Ab = A + (size_t)(m0 + srow) * KDIM + k0 + scol;
  const ushort* Bb = B + (size_t)(n0 + srow) * KDIM + k0 + scol;
  for (int kt = 0; kt < KSP / 64; ++kt) {
    __syncthreads();
#pragma unroll
    for (int r = 0; r < 2; ++r)
      async16(Ab + (size_t)(r * 32) * KDIM + kt * 64, &As[(srow + r * 32) * 64 + scol]);
#pragma unroll
    for (int r = 0; r < 4; ++r)
      async16(Bb + (size_t)(r * 32) * KDIM + kt * 64, &Bs[(srow + r * 32) * 64 + scol]);
    __syncthreads();
#pragma unroll
    for (int kk = 0; kk < 64; kk += 32) {
      v8bf a[2], b[4];
#pragma unroll
      for (int i = 0; i < 2; ++i)
        a[i] = *(const v8bf*)&As[(wm * 32 + i * 16 + lm) * 64 + kk + quad * 8];
#pragma unroll
      for (int j = 0; j < 4; ++j)
        b[j] = *(const v8bf*)&Bs[(wn * 64 + j * 16 + lm) * 64 + kk + quad * 8];
#pragma unroll
      for (int i = 0; i < 2; ++i)
#pragma unroll
        for (int j = 0; j < 4; ++j)
          acc[i][j] = __builtin_amdgcn_mfma_f32_16x16x32_bf16(a[i], b[j], acc[i][j], 0, 0, 0);
    }
  }
  float* Pb = P + (size_t)ks * MPAD * 256;
#pragma unroll
  for (int i = 0; i < 2; ++i)
#pragma unroll
    for (int j = 0; j < 4; ++j) {
      int row = m0 + wm * 32 + i * 16 + quad * 4;
      int col = n0 + wn * 64 + j * 16 + lm;
#pragma unroll
      for (int r = 0; r < 4; ++r)
        Pb[(size_t)(row + r) * 256 + col] = acc[i][j][r];
    }
}

// GEMM2 with fused split-K reduce: A-tile = sum of 7 P-partials + b1 + relu,
// packed bf16 into XOR-swizzled LDS; then K=256 MFMA loop + cls/reg heads.
__global__ __launch_bounds__(256) void k_gemm2(const float* __restrict__ P,
                                               const float* __restrict__ b1,
                                               const ushort* __restrict__ w2t,
                                               const float* __restrict__ b2,
                                               const float* __restrict__ wcls,
                                               const float* __restrict__ bcls,
                                               const float* __restrict__ wreg,
                                               const float* __restrict__ breg,
                                               float* __restrict__ out) {
  __shared__ ushort HsA[64 * 256];   // 32 KB swizzled A (bf16)
  __shared__ ushort Bs2[256 * 64];
  __shared__ float Hs[64 * 257];
  int tid = threadIdx.x;
  int r0 = blockIdx.x * 64;
  int lane = tid & 63, wv = tid >> 6;
  int lm = lane & 15, quad = lane >> 4;
  int srow = tid >> 3, scol = (tid & 7) * 8;
  // ---- stage A: split-K sum + b1 + relu -> bf16 LDS ----
  uint* H = (uint*)HsA;
  for (int it = 0; it < 16; ++it) {
    int e = it * 256 + tid;          // 0..4095
    int row = e >> 6;                // 0..63
    int c4 = e & 63;                 // float4 column (16B = 4 ch)
    float4 s = {0.f, 0.f, 0.f, 0.f};
#pragma unroll
    for (int ks = 0; ks < SPLITK; ++ks) {
      float4 v = ((const float4*)P)[((size_t)ks * MPAD + r0 + row) * 64 + c4];
      s.x += v.x; s.y += v.y; s.z += v.z; s.w += v.w;
    }
    int col = c4 * 4;
    s.x = fmaxf(s.x + b1[col + 0], 0.f);
    s.y = fmaxf(s.y + b1[col + 1], 0.f);
    s.z = fmaxf(s.z + b1[col + 2], 0.f);
    s.w = fmaxf(s.w + b1[col + 3], 0.f);
    int cs = (c4 >> 1) ^ (row & 7);            // 16B-chunk swizzle
    int ui = row * 128 + cs * 4 + (c4 & 1) * 2;
    H[ui]     = packbf(s.x, s.y);
    H[ui + 1] = packbf(s.z, s.w);
  }
  v4f acc[16];
#pragma unroll
  for (int j = 0; j < 16; ++j) acc[j] = (v4f){0.f, 0.f, 0.f, 0.f};
  int arow = wv * 16 + lm;
  int asw = (arow & 7) << 3;         // ushort-index swizzle (8 bf16 = 16B)
  for (int kt = 0; kt < 4; ++kt) {
    __syncthreads();
#pragma unroll
    for (int r = 0; r < 8; ++r)
      async16(w2t + (size_t)(srow + r * 32) * 256 + kt * 64 + scol,
              &Bs2[(srow + r * 32) * 64 + scol]);
    __syncthreads();
#pragma unroll
    for (int kk = 0; kk < 64; kk += 32) {
      v8bf a = *(const v8bf*)&HsA[arow * 256 + ((kt * 64 + kk + quad * 8) ^ asw)];
#pragma unroll
      for (int j = 0; j < 16; ++j) {
        v8bf b = *(const v8bf*)&Bs2[(j * 16 + lm) * 64 + kk + quad * 8];
        acc[j] = __builtin_amdgcn_mfma_f32_16x16x32_bf16(a, b, acc[j], 0, 0, 0);
      }
    }
  }
#pragma unroll
  for (int j = 0; j < 16; ++j) {
    int nn = j * 16 + lm;
    float bb = b2[nn];
#pragma unroll
    for (int r = 0; r < 4; ++r) {
      int row = wv * 16 + quad * 4 + r;
      Hs[row * 257 + nn] = fmaxf(acc[j][r] + bb, 0.f);
    }
  }
  __syncthreads();
  for (int o = tid; o < 384; o += 256) {
    int hd = o >> 6, r = o & 63;
    int grow = r0 + r;
    float d = 0.f;
    if (hd < 2) {
      for (int k = 0; k < 256; ++k) d += Hs[r * 257 + k] * wcls[k * 2 + hd];
      d += bcls[hd];
      if (grow < NROI) out[grow * 2 + hd] = d;
    } else {
      int h4 = hd - 2;
      for (int k = 0; k < 256; ++k) d += Hs[r * 257 + k] * wreg[k * 4 + h4];
      d += breg[h4];
      if (grow < NROI) out[4000 + grow * 4 + h4] = d;
    }
  }
}

extern "C" void kernel_launch(void* const* d_in, const int* in_sizes, int n_in,
                              void* d_out, int out_size, void* d_ws, size_t ws_size,
                              hipStream_t stream) {
  const float* features = (const float*)d_in[0];
  const int* rois = (const int*)d_in[1];
  const float* w1 = (const float*)d_in[2];
  const float* b1 = (const float*)d_in[3];
  const float* w2 = (const float*)d_in[4];
  const float* b2 = (const float*)d_in[5];
  const float* wcls = (const float*)d_in[6];
  const float* bcls = (const float*)d_in[7];
  const float* wreg = (const float*)d_in[8];
  const float* breg = (const float*)d_in[9];
  char* ws = (char*)d_ws;
  ushort* ft  = (ushort*)(ws + 0);          // 57,802,752 B
  ushort* w1t = (ushort*)(ws + 57802752);   //  6,422,528 B
  ushort* w2t = (ushort*)(ws + 64225280);   //    131,072 B
  ushort* rf  = (ushort*)(ws + 64356352);   // 51,380,224 B (2048 rows; rows
                                            // 2000+ are GEMM padding)
  // perm lives in rf's padding rows (read by gemm1 as harmless tiny bf16)
  int*    perm = (int*)(ws + 64356352 + (size_t)NROI * KDIM * 2);
  float*  P   = (float*)(ws + 115736576);   // 14,680,064 B used
  float* out = (float*)d_out;

  hipLaunchKernelGGL(k_trprep, dim3(NTRB + 425), dim3(256), 0, stream,
                     features, (uint*)ft, w1, (uint*)w1t, w2, w2t, rois, perm);
  hipLaunchKernelGGL(k_pool, dim3(NROI * 7), dim3(64), 0, stream, rois, perm,
                     (const uint2*)ft, (uint2*)rf);
  hipLaunchKernelGGL(k_gemm1, dim3(32, 2, SPLITK), dim3(256), 0, stream, rf, w1t, P);
  hipLaunchKernelGGL(k_gemm2, dim3(32), dim3(256), 0, stream, P, b1, w2t, b2,
                     wcls, bcls, wreg, breg, out);
}